// Round 7
// baseline (290.230 us; speedup 1.0000x reference)
//
#include <hip/hip_runtime.h>

#define TOK 8192   // B*S
#define DIM 512    // D
#define NE  32     // experts
#define KTOT (NE * DIM)

#define BM 128
#define BN 128
#define BK 64

typedef float f32x4  __attribute__((ext_vector_type(4)));
typedef float f32x16 __attribute__((ext_vector_type(16)));
typedef short s16x8  __attribute__((ext_vector_type(8)));

typedef const void __attribute__((address_space(1)))* gp1_t;
typedef void __attribute__((address_space(3)))* lp3_t;

__device__ __forceinline__ void gl_lds16(const void* g, void* l) {
    __builtin_amdgcn_global_load_lds((gp1_t)g, (lp3_t)l, 16, 0, 0);
}

// A tile: 128 rows x 128B = 16KB; 256 thr x 16B = 4KB/round -> 4 rounds
__device__ __forceinline__ void stageA(const ushort* g, char* l) {
#pragma unroll
    for (int r = 0; r < 4; ++r)
        gl_lds16(g + (size_t)r * 32 * DIM, l + r * 4096);
}

__device__ __forceinline__ ushort f2bf(float f) {
    unsigned u = __builtin_bit_cast(unsigned, f);
    unsigned r = (u + 0x7fffu + ((u >> 16) & 1u)) >> 16;
    return (ushort)r;
}

// ---- fused prep: blocks [0,2048) transpose+convert W; [2048,3072) gates+cvt x
__global__ __launch_bounds__(256) void k_prep(const float* __restrict__ w,
                                              ushort* __restrict__ wt,
                                              const float* __restrict__ x,
                                              const float* __restrict__ gw,
                                              const float* __restrict__ gb,
                                              float* __restrict__ G,
                                              ushort* __restrict__ xb) {
    __shared__ __align__(16) char smem[64 * 65 * 4];
    const int bx = blockIdx.x;
    const int tid = threadIdx.x;
    if (bx < 2048) {
        // ---- Wt[f][e*512+d] = bf16(w[e][d][f]), 64x64 tile ----
        float (*tile)[65] = (float(*)[65])smem;
        const int e = bx >> 6;
        const int f0 = ((bx >> 3) & 7) * 64;
        const int d0 = (bx & 7) * 64;
        const int tx = tid & 63, ty = tid >> 6;  // ty 0..3
        const float* we = w + (size_t)e * DIM * DIM;
#pragma unroll
        for (int i = ty; i < 64; i += 4)
            tile[i][tx] = we[(size_t)(d0 + i) * DIM + f0 + tx];
        __syncthreads();
#pragma unroll
        for (int i = ty; i < 64; i += 4)
            wt[(size_t)(f0 + i) * KTOT + e * DIM + d0 + tx] = f2bf(tile[tx][i]);
    } else {
        // ---- gates (8 tokens/block, shfl softmax) + x -> bf16 ----
        float* xs = (float*)smem;
        const int t0 = (bx - 2048) * 8;
        const float* xBase = x + (size_t)t0 * DIM;
#pragma unroll
        for (int k = 0; k < 4; ++k) {
            int i4 = (k * 256 + tid) * 4;
            float4 v = *(const float4*)(xBase + i4);
            xs[i4 + 0] = v.x; xs[i4 + 1] = v.y; xs[i4 + 2] = v.z; xs[i4 + 3] = v.w;
            ushort4 o;
            o.x = f2bf(v.x); o.y = f2bf(v.y); o.z = f2bf(v.z); o.w = f2bf(v.w);
            *(ushort4*)(xb + (size_t)t0 * DIM + i4) = o;
        }
        __syncthreads();
        const int tok = tid >> 5;   // 0..7
        const int e = tid & 31;
        float l = gb[e];
        const float* xr = xs + tok * DIM;
#pragma unroll 8
        for (int d = 0; d < DIM; ++d)
            l += xr[d] * gw[d * NE + e];
        float mx = l;
#pragma unroll
        for (int m = 16; m >= 1; m >>= 1) mx = fmaxf(mx, __shfl_xor(mx, m));
        float ex = expf(l - mx);
        float s = ex;
#pragma unroll
        for (int m = 16; m >= 1; m >>= 1) s += __shfl_xor(s, m);
        G[(size_t)(t0 + tok) * NE + e] = ex / s;
    }
}

// -------- main GEMM v8: v2 geometry + 2-phase counted-vmcnt schedule --------
// v2 (148us) analysis: per-iter wall 2780 cyc vs matrix 1033 + LDS ~1800
// serialized inside one barrier pair -> T3+T4 target. v8 keeps v2's exact
// geometry/fragments/fold/epilogue (proven, VGPR 104) and changes ONLY sync:
//  - B: 3-slot ring (3x16KB), staged TWO ahead (4 gl_lds per tile, split
//    2+2 across the two phases); uniform incremental slot scalars.
//  - iter entry: s_waitcnt vmcnt(4) + raw s_barrier => publishes B(g) while
//    B(g+1)'s 4 ops stay in flight across the barrier. vmcnt(0) only g=127.
//  - per iter, 2 phases split at nj, separated by a bare s_barrier; each:
//    {issue 2 gl_lds of B(g+2) | ds_read 4 breg (+greg/areg ph1) |
//     setprio(1) 8xMFMA setprio(0) | fold}.
//  - A: single 16KB buffer; frags->regs at ee==0; restaged at ee==1 ISSUED
//    FIRST so vmcnt order stays uniform. Verified: entering ee==2,
//    outstanding = A(4)+B(g+2)(4) newest; wait(4) keeps B(g+2), drains A+B(g+1->read now). 
//  - no unroll, no sched_barrier(0), single "memory" asm per iter (v6's
//    spill trap avoided; v3's missing-phase-structure trap avoided).
// LDS: A 16 + B 48 + Gs 8 = 72KB -> 2 blocks/CU, 8 waves/CU.
__global__ __launch_bounds__(256, 2) void k_moe_gemm(const ushort* __restrict__ xb,
                                                     const ushort* __restrict__ wt,
                                                     const float* __restrict__ G,
                                                     float* __restrict__ out0,
                                                     float* __restrict__ out1) {
    __shared__ __align__(16) ushort As[BM * BK];      // 16 KB single buffer
    __shared__ __align__(16) ushort Bs[3][BN * BK];   // 3 x 16 KB ring
    __shared__ float Gs[16][BM];                      // 8 KB

    const int tid = threadIdx.x;
    const int m0 = blockIdx.y * BM;
    const int n0 = blockIdx.x * BN;
    const int e0 = blockIdx.z * 16;
    float* __restrict__ dst = blockIdx.z ? out1 : out0;

    for (int i = tid; i < 16 * BM; i += 256) {
        int e = i >> 7, r = i & 127;
        Gs[e][r] = G[(size_t)(m0 + r) * NE + e0 + e];
    }

    const int lane = tid & 63;
    const int wave = tid >> 6;          // 0..3
    const int wm = (wave & 1) * 64;
    const int wn = (wave >> 1) * 64;
    const int l31 = lane & 31;
    const int hi = lane >> 5;           // 0..1
    const int key = l31 & 7;

    // frag read offsets: row*128 + ((2s+hi) ^ (row&7))*16   (row&7 == key)
    int chunkOff[4], rowOffA[2], rowOffB[2];
#pragma unroll
    for (int s = 0; s < 4; ++s) chunkOff[s] = ((2 * s + hi) ^ key) * 16;
#pragma unroll
    for (int i = 0; i < 2; ++i) {
        rowOffA[i] = (wm + i * 32 + l31) * 128;
        rowOffB[i] = (wn + i * 32 + l31) * 128;
    }

    // staging map: 256 thr x 16B = 4KB/round = 32 rows of 128B
    const int srow = tid >> 3;                       // 0..31
    const int scol = ((tid & 7) ^ (srow & 7)) * 8;   // swizzled global column
    const ushort* aBase = xb + (size_t)(m0 + srow) * DIM + scol;
    const ushort* bBase = wt + (size_t)(n0 + srow) * KTOT + (size_t)e0 * DIM + scol;
    const int ldsOff = tid * 16;

    f32x16 zv16;
#pragma unroll
    for (int j = 0; j < 16; ++j) zv16[j] = 0.f;
    f32x16 acc[2][2];
#pragma unroll
    for (int i = 0; i < 2; ++i)
#pragma unroll
        for (int j = 0; j < 2; ++j) acc[i][j] = zv16;

    // prologue: A(0) [4 ops, oldest], B(0) [4], B(1) [4]. No drain, no
    // barrier here: iter-0 entry wait(4) drains A(0)+B(0), keeps B(1).
    stageA(aBase, (char*)As + ldsOff);
    {
        char* b0 = (char*)Bs[0] + ldsOff;
        char* b1 = (char*)Bs[1] + ldsOff;
#pragma unroll
        for (int r = 0; r < 4; ++r) gl_lds16(bBase + (size_t)r * 32 * KTOT, b0 + r * 4096);
#pragma unroll
        for (int r = 0; r < 4; ++r) gl_lds16(bBase + (size_t)1 * DIM + (size_t)r * 32 * KTOT, b1 + r * 4096);
    }
    // drain own Gs ds_writes so the iter-0 barrier publishes Gs block-wide
    asm volatile("s_waitcnt lgkmcnt(0)" ::: "memory");

    const char* BsAll = (const char*)&Bs[0][0];
    int rsl = 0;   // ring slot holding tile g
    int wsl = 2;   // ring slot receiving tile g+2

    s16x8 areg[2][4];

#pragma unroll 1
    for (int kt = 0; kt < 8; ++kt) {
#pragma unroll 1
        for (int ee = 0; ee < 16; ++ee) {
            const int g = kt * 16 + ee;

            // ---- publish B(g) (and older A); keep B(g+1) in flight ----
            if (g == 127) asm volatile("s_waitcnt vmcnt(0)" ::: "memory");
            else          asm volatile("s_waitcnt vmcnt(4)" ::: "memory");
            __builtin_amdgcn_s_barrier();

            const int gn = g + 2;
            const ushort* bN = bBase + (size_t)(gn & 15) * DIM + (gn >> 4) * BK;
            char* bDst = (char*)BsAll + wsl * 16384 + ldsOff;

            // =================== phase 1 (nj = 0) ===================
            // A restage first at ee==1 (oldest in vmcnt stream)
            if (ee == 1 && kt < 7)
                stageA(aBase + (kt + 1) * BK, (char*)As + ldsOff);
            if (gn < 128) {
                gl_lds16(bN, bDst);
                gl_lds16(bN + (size_t)32 * KTOT, bDst + 4096);
            }

            if (ee == 0) {
#pragma unroll
                for (int mi = 0; mi < 2; ++mi)
#pragma unroll
                    for (int s = 0; s < 4; ++s)
                        areg[mi][s] = *(const s16x8*)((const char*)As + rowOffA[mi] + chunkOff[s]);
            }

            const char* Bb = BsAll + rsl * 16384;
            s16x8 breg0[4];
#pragma unroll
            for (int s = 0; s < 4; ++s)
                breg0[s] = *(const s16x8*)(Bb + rowOffB[0] + chunkOff[s]);

            f32x4 greg[2][4];
#pragma unroll
            for (int mi = 0; mi < 2; ++mi)
#pragma unroll
                for (int gq = 0; gq < 4; ++gq)
                    greg[mi][gq] = *(const f32x4*)&Gs[ee][wm + mi * 32 + 8 * gq + 4 * hi];

            __builtin_amdgcn_s_setprio(1);
            f32x16 p0 = __builtin_amdgcn_mfma_f32_32x32x16_bf16(areg[0][0], breg0[0], zv16, 0, 0, 0);
            f32x16 p1 = __builtin_amdgcn_mfma_f32_32x32x16_bf16(areg[1][0], breg0[0], zv16, 0, 0, 0);
#pragma unroll
            for (int s = 1; s < 4; ++s) {
                p0 = __builtin_amdgcn_mfma_f32_32x32x16_bf16(areg[0][s], breg0[s], p0, 0, 0, 0);
                p1 = __builtin_amdgcn_mfma_f32_32x32x16_bf16(areg[1][s], breg0[s], p1, 0, 0, 0);
            }
            __builtin_amdgcn_s_setprio(0);
#pragma unroll
            for (int gq = 0; gq < 4; ++gq)
#pragma unroll
                for (int j = 0; j < 4; ++j) {
                    acc[0][0][4 * gq + j] += greg[0][gq][j] * p0[4 * gq + j];
                    acc[1][0][4 * gq + j] += greg[1][gq][j] * p1[4 * gq + j];
                }

            __builtin_amdgcn_s_barrier();   // phase rendezvous (no drain)

            // =================== phase 2 (nj = 1) ===================
            if (gn < 128) {
                gl_lds16(bN + (size_t)64 * KTOT, bDst + 8192);
                gl_lds16(bN + (size_t)96 * KTOT, bDst + 12288);
            }

            s16x8 breg1[4];
#pragma unroll
            for (int s = 0; s < 4; ++s)
                breg1[s] = *(const s16x8*)(Bb + rowOffB[1] + chunkOff[s]);

            __builtin_amdgcn_s_setprio(1);
            f32x16 q0 = __builtin_amdgcn_mfma_f32_32x32x16_bf16(areg[0][0], breg1[0], zv16, 0, 0, 0);
            f32x16 q1 = __builtin_amdgcn_mfma_f32_32x32x16_bf16(areg[1][0], breg1[0], zv16, 0, 0, 0);
#pragma unroll
            for (int s = 1; s < 4; ++s) {
                q0 = __builtin_amdgcn_mfma_f32_32x32x16_bf16(areg[0][s], breg1[s], q0, 0, 0, 0);
                q1 = __builtin_amdgcn_mfma_f32_32x32x16_bf16(areg[1][s], breg1[s], q1, 0, 0, 0);
            }
            __builtin_amdgcn_s_setprio(0);
#pragma unroll
            for (int gq = 0; gq < 4; ++gq)
#pragma unroll
                for (int j = 0; j < 4; ++j) {
                    acc[0][1][4 * gq + j] += greg[0][gq][j] * q0[4 * gq + j];
                    acc[1][1][4 * gq + j] += greg[1][gq][j] * q1[4 * gq + j];
                }

            // advance ring (uniform scalars)
            rsl = (rsl == 2) ? 0 : rsl + 1;
            wsl = (wsl == 2) ? 0 : wsl + 1;
        }
    }

    // epilogue: C/D layout col=lane&31, row=(reg&3)+8*(reg>>2)+4*hi
#pragma unroll
    for (int mi = 0; mi < 2; ++mi)
#pragma unroll
        for (int nj = 0; nj < 2; ++nj) {
            const int col = n0 + wn + nj * 32 + l31;
#pragma unroll
            for (int gq = 0; gq < 4; ++gq) {
                float* p = dst + (size_t)(m0 + wm + mi * 32 + 8 * gq + 4 * hi) * DIM + col;
                p[0 * DIM] = acc[mi][nj][4 * gq + 0];
                p[1 * DIM] = acc[mi][nj][4 * gq + 1];
                p[2 * DIM] = acc[mi][nj][4 * gq + 2];
                p[3 * DIM] = acc[mi][nj][4 * gq + 3];
            }
        }
}

// ---- deterministic two-phase sum: out += P (both fully written upstream) ----
__global__ __launch_bounds__(256) void k_reduce(float* __restrict__ out,
                                                const float* __restrict__ P) {
    int i = (blockIdx.x * 256 + threadIdx.x) * 4;
    float4 a = *(const float4*)(out + i);
    float4 b = *(const float4*)(P + i);
    a.x += b.x; a.y += b.y; a.z += b.z; a.w += b.w;
    *(float4*)(out + i) = a;
}

extern "C" void kernel_launch(void* const* d_in, const int* in_sizes, int n_in,
                              void* d_out, int out_size, void* d_ws, size_t ws_size,
                              hipStream_t stream) {
    const float* x  = (const float*)d_in[0];   // [8192][512]
    const float* gw = (const float*)d_in[1];   // [512][32]
    const float* gb = (const float*)d_in[2];   // [32]
    const float* w  = (const float*)d_in[3];   // [32][512][512]
    float* out = (float*)d_out;                // [8192][512] fp32

    char* ws = (char*)d_ws;
    ushort* xb = (ushort*)ws;                            //  0..8 MiB
    ushort* wt = (ushort*)(ws + (8u << 20));             //  8..24 MiB
    float*  G  = (float*)(ws + (24u << 20));             // 24..25 MiB
    float*  P  = (float*)(ws + (25u << 20));             // 25..41 MiB

    k_prep<<<dim3(2048 + TOK / 8), dim3(256), 0, stream>>>(w, wt, x, gw, gb, G, xb);
    k_moe_gemm<<<dim3(DIM / BN, TOK / BM, 2), dim3(256), 0, stream>>>(xb, wt, G, out, P);
    k_reduce<<<dim3(TOK * DIM / 1024), dim3(256), 0, stream>>>(out, P);
}